// Round 4
// baseline (912.282 us; speedup 1.0000x reference)
//
#include <hip/hip_runtime.h>
#include <math.h>
#include <stdint.h>

typedef _Float16 f16x8 __attribute__((ext_vector_type(8)));
typedef float    f32x4 __attribute__((ext_vector_type(4)));

#define NB    8192
#define V_    25
#define KS_   0.25505003938643f      // 32^-0.5 * log2(e)

// ws layout: [0, 512K) = W' (gamma-folded) hi/lo MFMA B-fragments
//            [512K, 512K+2K) = s1[512] f32 :  sum_c gamma[c]*W[e][c]
//            [512K+2K, +4K)  = s2[512] f32 :  sum_c beta[c]*W[e][c] + b[e]
// LN folded into GEMM epilogue: P = rs*(G - mu*s1) + s2, G = x_raw . W'^T.
// ---------------------------------------------------------------------------
__global__ __launch_bounds__(256)
void prep_w(const float* __restrict__ W, const float* __restrict__ gamma,
            const float* __restrict__ beta, const float* __restrict__ bias,
            char* __restrict__ ws) {
    const int blk = blockIdx.x;
    if (blk < 64) {
        // B-fragment packing (as before) with gamma folded in.
        int tid  = blk * 256 + threadIdx.x;
        int lane = tid & 63;
        int idx  = tid >> 6;                     // 0..255
        int C    = idx >> 4;
        int T2   = idx & 15;
        int half = C >> 3, ch = C & 7;
        int l15  = lane & 15, q4 = lane >> 4;
        int col0 = ch*32 + q4*8;
        const float* src = W + (size_t)(half*256 + T2*16 + l15) * 256 + col0;
        f16x8 hi, lo;
        #pragma unroll
        for (int j = 0; j < 8; ++j) {
            float w = src[j] * gamma[col0 + j];
            _Float16 hh = (_Float16)w;
            hi[j] = hh;
            lo[j] = (_Float16)(w - (float)hh);
        }
        char* base = ws + (size_t)idx * 2048 + lane * 16;
        *(f16x8*)base          = hi;
        *(f16x8*)(base + 1024) = lo;
    } else {
        // s1/s2 row sums (blocks 64,65 -> e = 0..511)
        int e = (blk - 64) * 256 + threadIdx.x;
        const float* wr = W + (size_t)e * 256;
        float a1 = 0.f, a2 = 0.f;
        #pragma unroll 8
        for (int c = 0; c < 256; ++c) {
            float w = wr[c];
            a1 += w * gamma[c];
            a2 += w * beta[c];
        }
        a2 += bias[e];
        ((float*)(ws + 512*1024))[e]        = a1;
        ((float*)(ws + 512*1024 + 2048))[e] = a2;
    }
}

// ---------------------------------------------------------------------------
// LDS: 25-row staged tiles (raw x hi/lo, XOR-swizzled pitch-256) aliased with
// the per-wave QK staging. 25856 B total -> 5 blocks/CU even at a 128K cap.
// ---------------------------------------------------------------------------
struct __align__(16) SMem {
    union {
        struct {
            _Float16 ysh[25][256];              // 12800 B : raw-x hi [v][c]
            _Float16 ysl[25][256];              // 12800 B : raw-x lo
        } g;                                    // 25600 B ; byte off within a
        // row ^= ((row&7)<<4): GEMM b128 frag reads conflict-free.
        _Float16 qk[4][2][25][64];              // 25600 B : per-wave QK staging
        // qk[wave][hi/lo][row v][col 0..31=Q, 32..63=K], same XOR swizzle.
    } u;
    float s_mu[32];
    float s_rs[32];
};

__global__ __launch_bounds__(256, 5)
void fused_ln_qk_attn(const float* __restrict__ x,
                      const _Float16* __restrict__ wsp,
                      const float* __restrict__ s1p,
                      const float* __restrict__ s2p,
                      float* __restrict__ out)
{
    __shared__ SMem sm;

    const int tid  = threadIdx.x;
    const int lane = tid & 63;
    const int wv   = tid >> 6;
    const int l15  = lane & 15;
    const int q4   = lane >> 4;
    const int nt   = blockIdx.x;
    const int n    = nt >> 7;
    const int t    = nt & 127;
    const int base = n * 819200 + t * 25;       // x[n][c][t][v]

    char* yh = (char*)&sm.u.g.ysh[0][0];
    char* yl = yh + 12800;

    // ---------------- Phase 0: stage raw x as f16 hi/lo (c = tid) ------------
    {
        const float* xr = x + base + tid * 3200;
        #pragma unroll
        for (int v = 0; v < V_; ++v) {
            float val = xr[v];
            _Float16 h = (_Float16)val;
            const int off = (v*512 + tid*2) ^ ((v & 7) << 4);
            *(_Float16*)(yh + off) = h;
            *(_Float16*)(yl + off) = (_Float16)(val - (float)h);
        }
    }
    __syncthreads();

    // ---------------- LN stats (thread = (v, j); hi+lo reconstruct) ----------
    {
        const int v  = tid >> 3;
        const int vc = v < 24 ? v : 24;         // rows 25..31 don't exist: clamp
        const int j  = tid & 7;
        float a1 = 0.f, a2 = 0.f;
        #pragma unroll
        for (int m2 = 0; m2 < 4; ++m2) {
            const int off = (vc*512 + (j*32 + m2*8)*2) ^ ((vc & 7) << 4);
            f16x8 hv = *(const f16x8*)(yh + off);
            f16x8 lv = *(const f16x8*)(yl + off);
            #pragma unroll
            for (int e = 0; e < 8; ++e) {
                float val = (float)hv[e] + (float)lv[e];
                a1 += val; a2 += val * val;
            }
        }
        a1 += __shfl_xor(a1, 1); a2 += __shfl_xor(a2, 1);
        a1 += __shfl_xor(a1, 2); a2 += __shfl_xor(a2, 2);
        a1 += __shfl_xor(a1, 4); a2 += __shfl_xor(a2, 4);
        if (j == 0) {
            if (v < V_) {
                float mu  = a1 * (1.0f/256.0f);
                float var = a2 * (1.0f/256.0f) - mu * mu;
                sm.s_mu[v] = mu;
                sm.s_rs[v] = rsqrtf(var + 1e-5f);
            } else { sm.s_mu[v] = 0.0f; sm.s_rs[v] = 0.0f; }
        }
    }
    // NO barrier: GEMM below only READS ysh/ysl (no writer until post-GEMM
    // sync); s_mu/s_rs visibility is covered by that same sync.

    // s1/s2 for this lane's 16 output columns (issued early, L2-hot)
    float sv1[2][4], sv2[2][4];
    #pragma unroll
    for (int h = 0; h < 2; ++h)
        #pragma unroll
        for (int j = 0; j < 4; ++j) {
            const int e = h*256 + (wv*4 + j)*16 + l15;
            sv1[h][j] = s1p[e];
            sv2[h][j] = s2p[e];
        }

    // ---------------- GEMM: G[v][e] = sum_c x[v][c]*W'[e][c], f16 split-x3 ---
    f32x4 acc[2][2][4];
    #pragma unroll
    for (int h = 0; h < 2; ++h)
        #pragma unroll
        for (int m = 0; m < 2; ++m)
            #pragma unroll
            for (int j = 0; j < 4; ++j)
                acc[h][m][j] = (f32x4){0.f, 0.f, 0.f, 0.f};

    const char* bbase = (const char*)wsp + (size_t)lane * 16 + (size_t)(wv*4) * 2048;
    const int r1 = (16 + l15) < 24 ? (16 + l15) : 24;   // row clamp (acc rows
                                                        // >=25 masked later)
    for (int ch = 0; ch < 8; ++ch) {
        const int kb = (ch*32 + q4*8) * 2;
        const int o0 = (l15*512 + kb) ^ ((l15 & 7) << 4);
        const int o1 = (r1 *512 + kb) ^ ((r1  & 7) << 4);
        f16x8 Ah0 = *(const f16x8*)(yh + o0);
        f16x8 Ah1 = *(const f16x8*)(yh + o1);
        f16x8 Al0 = *(const f16x8*)(yl + o0);
        f16x8 Al1 = *(const f16x8*)(yl + o1);
        #pragma unroll
        for (int half = 0; half < 2; ++half) {
            const char* cb = bbase + (size_t)(half*8 + ch) * 16 * 2048;
            #pragma unroll
            for (int j = 0; j < 4; ++j) {
                const char* pj = cb + (size_t)j * 2048;
                f16x8 Bh = *(const f16x8*)pj;
                f16x8 Bl = *(const f16x8*)(pj + 1024);
                acc[half][0][j] = __builtin_amdgcn_mfma_f32_16x16x32_f16(Ah0, Bh, acc[half][0][j], 0, 0, 0);
                acc[half][0][j] = __builtin_amdgcn_mfma_f32_16x16x32_f16(Al0, Bh, acc[half][0][j], 0, 0, 0);
                acc[half][0][j] = __builtin_amdgcn_mfma_f32_16x16x32_f16(Ah0, Bl, acc[half][0][j], 0, 0, 0);
                acc[half][1][j] = __builtin_amdgcn_mfma_f32_16x16x32_f16(Ah1, Bh, acc[half][1][j], 0, 0, 0);
                acc[half][1][j] = __builtin_amdgcn_mfma_f32_16x16x32_f16(Al1, Bh, acc[half][1][j], 0, 0, 0);
                acc[half][1][j] = __builtin_amdgcn_mfma_f32_16x16x32_f16(Ah1, Bl, acc[half][1][j], 0, 0, 0);
            }
        }
    }
    __syncthreads();   // ysh/ysl reads done; s_mu visible; qk may be written

    // per-row LN constants for this thread's 8 accumulator rows
    f32x4 mu4[2], rs4[2];
    mu4[0] = *(const f32x4*)&sm.s_mu[q4*4];
    mu4[1] = *(const f32x4*)&sm.s_mu[16 + q4*4];
    rs4[0] = *(const f32x4*)&sm.s_rs[q4*4];
    rs4[1] = *(const f32x4*)&sm.s_rs[16 + q4*4];

    // ---------------- Attention via MFMA (per-wave, 2 heads) ------------------
    char* qh = (char*)&sm.u.qk[wv][0][0][0];
    char* ql = qh + 3200;

    #pragma unroll
    for (int hh = 0; hh < 2; ++hh) {
        // ---- LN epilogue + stage this head's Q,K (hi/lo f16) ----
        #pragma unroll
        for (int half = 0; half < 2; ++half)
            #pragma unroll
            for (int jj = 0; jj < 2; ++jj) {
                const int   j  = 2*hh + jj;
                const float c1 = sv1[half][j];
                const float c2 = sv2[half][j];
                const int  col = half*32 + jj*16 + l15;
                #pragma unroll
                for (int mt = 0; mt < 2; ++mt)
                    #pragma unroll
                    for (int r = 0; r < 4; ++r) {
                        const int row = mt*16 + q4*4 + r;
                        if (row < V_) {
                            float tv  = fmaf(-mu4[mt][r], c1, acc[half][mt][j][r]);
                            float val = fmaf(rs4[mt][r], tv, c2);
                            _Float16 h = (_Float16)val;
                            const int off = (row*128 + col*2) ^ ((row & 7) << 4);
                            *(_Float16*)(qh + off) = h;
                            *(_Float16*)(ql + off) = (_Float16)(val - (float)h);
                        }
                    }
            }
        // same-wave DS ops are in-order; compiler inserts lgkmcnt waits

        // ---- fragment reads (A = K rows, B = Q rows); rows >=25 clamp to 24 --
        f16x8 Kh[2], Kl[2], Qh[2], Ql[2];
        #pragma unroll
        for (int tt = 0; tt < 2; ++tt) {
            int rr = tt*16 + l15; if (rr > 24) rr = 24;
            const int swz = (rr & 7) << 4;
            const int oK  = (rr*128 + 64 + q4*16) ^ swz;
            const int oQ  = (rr*128 +      q4*16) ^ swz;
            Kh[tt] = *(const f16x8*)(qh + oK);
            Kl[tt] = *(const f16x8*)(ql + oK);
            Qh[tt] = *(const f16x8*)(qh + oQ);
            Ql[tt] = *(const f16x8*)(ql + oQ);
        }

        // ---- D[jt][it] = K·Q^T, split-x3 (12 MFMA per head) ----
        f32x4 D[2][2];
        #pragma unroll
        for (int jt = 0; jt < 2; ++jt)
            #pragma unroll
            for (int it = 0; it < 2; ++it) {
                f32x4 d = (f32x4){0.f, 0.f, 0.f, 0.f};
                d = __builtin_amdgcn_mfma_f32_16x16x32_f16(Kh[jt], Qh[it], d, 0, 0, 0);
                d = __builtin_amdgcn_mfma_f32_16x16x32_f16(Kl[jt], Qh[it], d, 0, 0, 0);
                d = __builtin_amdgcn_mfma_f32_16x16x32_f16(Kh[jt], Ql[it], d, 0, 0, 0);
                D[jt][it] = d;
            }

        // ---- softmax over keys + store ----
        float* op = out + (size_t)nt * 5000 + (wv*2 + hh) * 625;
        #pragma unroll
        for (int it = 0; it < 2; ++it) {
            const int i = it*16 + l15;          // query index (col = l15)
            float pv[2][4];
            float mx = -3.0e38f;
            #pragma unroll
            for (int jt = 0; jt < 2; ++jt)
                #pragma unroll
                for (int r = 0; r < 4; ++r) {
                    const int j = jt*16 + q4*4 + r;   // key index (row)
                    float v = (j < V_) ? D[jt][it][r] : -3.0e38f;
                    pv[jt][r] = v;
                    mx = fmaxf(mx, v);
                }
            mx = fmaxf(mx, __shfl_xor(mx, 16));
            mx = fmaxf(mx, __shfl_xor(mx, 32));
            float sum = 0.0f;
            #pragma unroll
            for (int jt = 0; jt < 2; ++jt)
                #pragma unroll
                for (int r = 0; r < 4; ++r) {
                    float e = exp2f((pv[jt][r] - mx) * KS_);
                    pv[jt][r] = e;
                    sum += e;
                }
            sum += __shfl_xor(sum, 16);
            sum += __shfl_xor(sum, 32);
            const float rcp = 1.0f / sum;
            if (i < V_) {
                #pragma unroll
                for (int jt = 0; jt < 2; ++jt)
                    #pragma unroll
                    for (int r = 0; r < 4; ++r) {
                        const int j = jt*16 + q4*4 + r;
                        if (j < V_) op[i*25 + j] = pv[jt][r] * rcp;
                    }
            }
        }
    }
}

extern "C" void kernel_launch(void* const* d_in, const int* in_sizes, int n_in,
                              void* d_out, int out_size, void* d_ws, size_t ws_size,
                              hipStream_t stream) {
    const float* x     = (const float*)d_in[0];
    const float* gamma = (const float*)d_in[1];
    const float* beta  = (const float*)d_in[2];
    const float* W     = (const float*)d_in[3];
    const float* b     = (const float*)d_in[4];
    char* ws = (char*)d_ws;
    float* out = (float*)d_out;

    prep_w<<<dim3(66), dim3(256), 0, stream>>>(W, gamma, beta, b, ws);
    fused_ln_qk_attn<<<dim3(NB), dim3(256), 0, stream>>>(
        x, (const _Float16*)ws,
        (const float*)(ws + 512*1024),
        (const float*)(ws + 512*1024 + 2048),
        out);
}

// Round 5
// 605.154 us; speedup vs baseline: 1.5075x; 1.5075x over previous
//
#include <hip/hip_runtime.h>
#include <math.h>
#include <stdint.h>

typedef _Float16 f16x8 __attribute__((ext_vector_type(8)));
typedef float    f32x4 __attribute__((ext_vector_type(4)));

#define NB    8192
#define V_    25
#define KS_   0.25505003938643f      // 32^-0.5 * log2(e)

// ws layout: [0, 512K) = W' (gamma-folded) hi/lo MFMA B-fragments
//            [512K, 512K+2K) = s1[512] f32 :  sum_c gamma[c]*W[e][c]
//            [512K+2K, +4K)  = s2[512] f32 :  sum_c beta[c]*W[e][c] + b[e]
// LN folded into GEMM epilogue: P = rs*(G - mu*s1) + s2, G = x_raw . W'^T.
// ---------------------------------------------------------------------------
__global__ __launch_bounds__(256)
void prep_w(const float* __restrict__ W, const float* __restrict__ gamma,
            const float* __restrict__ beta, const float* __restrict__ bias,
            char* __restrict__ ws) {
    const int blk = blockIdx.x;
    if (blk < 64) {
        // B-fragment packing with gamma folded in.
        int tid  = blk * 256 + threadIdx.x;
        int lane = tid & 63;
        int idx  = tid >> 6;                     // 0..255
        int C    = idx >> 4;
        int T2   = idx & 15;
        int half = C >> 3, ch = C & 7;
        int l15  = lane & 15, q4 = lane >> 4;
        int col0 = ch*32 + q4*8;
        const float* src = W + (size_t)(half*256 + T2*16 + l15) * 256 + col0;
        f16x8 hi, lo;
        #pragma unroll
        for (int j = 0; j < 8; ++j) {
            float w = src[j] * gamma[col0 + j];
            _Float16 hh = (_Float16)w;
            hi[j] = hh;
            lo[j] = (_Float16)(w - (float)hh);
        }
        char* base = ws + (size_t)idx * 2048 + lane * 16;
        *(f16x8*)base          = hi;
        *(f16x8*)(base + 1024) = lo;
    } else {
        // s1/s2 row sums (blocks 64,65 -> e = 0..511)
        int e = (blk - 64) * 256 + threadIdx.x;
        const float* wr = W + (size_t)e * 256;
        float a1 = 0.f, a2 = 0.f;
        #pragma unroll 8
        for (int c = 0; c < 256; ++c) {
            float w = wr[c];
            a1 += w * gamma[c];
            a2 += w * beta[c];
        }
        a2 += bias[e];
        ((float*)(ws + 512*1024))[e]        = a1;
        ((float*)(ws + 512*1024 + 2048))[e] = a2;
    }
}

// ---------------------------------------------------------------------------
// LDS: 25-row staged tiles (raw x hi/lo, XOR-swizzled pitch-256) aliased with
// the per-wave QK staging. 25856 B total.
// Occupancy note: register-limited, NOT LDS-limited. (256,5) forces the
// unified VGPR+AGPR budget under ~102/thread -> acc spills to scratch
// (round 4: WRITE_SIZE 160MB -> 1.34GB, dur 321 -> 690us). Keep (256,4).
// ---------------------------------------------------------------------------
struct __align__(16) SMem {
    union {
        struct {
            _Float16 ysh[25][256];              // 12800 B : raw-x hi [v][c]
            _Float16 ysl[25][256];              // 12800 B : raw-x lo
        } g;                                    // 25600 B ; byte off within a
        // row ^= ((row&7)<<4): GEMM b128 frag reads conflict-free.
        _Float16 qk[4][2][25][64];              // 25600 B : per-wave QK staging
        // qk[wave][hi/lo][row v][col 0..31=Q, 32..63=K], same XOR swizzle.
    } u;
    float s_mu[32];
    float s_rs[32];
};

__global__ __launch_bounds__(256, 4)
void fused_ln_qk_attn(const float* __restrict__ x,
                      const _Float16* __restrict__ wsp,
                      const float* __restrict__ s1p,
                      const float* __restrict__ s2p,
                      float* __restrict__ out)
{
    __shared__ SMem sm;

    const int tid  = threadIdx.x;
    const int lane = tid & 63;
    const int wv   = tid >> 6;
    const int l15  = lane & 15;
    const int q4   = lane >> 4;
    const int nt   = blockIdx.x;
    const int n    = nt >> 7;
    const int t    = nt & 127;
    const int base = n * 819200 + t * 25;       // x[n][c][t][v]

    char* yh = (char*)&sm.u.g.ysh[0][0];
    char* yl = yh + 12800;

    // ---------------- Phase 0: stage raw x as f16 hi/lo (c = tid) ------------
    {
        const float* xr = x + base + tid * 3200;
        #pragma unroll
        for (int v = 0; v < V_; ++v) {
            float val = xr[v];
            _Float16 h = (_Float16)val;
            const int off = (v*512 + tid*2) ^ ((v & 7) << 4);
            *(_Float16*)(yh + off) = h;
            *(_Float16*)(yl + off) = (_Float16)(val - (float)h);
        }
    }
    __syncthreads();

    // ---------------- LN stats (thread = (v, j); hi+lo reconstruct) ----------
    {
        const int v  = tid >> 3;
        const int vc = v < 24 ? v : 24;         // rows 25..31 don't exist: clamp
        const int j  = tid & 7;
        float a1 = 0.f, a2 = 0.f;
        #pragma unroll
        for (int m2 = 0; m2 < 4; ++m2) {
            const int off = (vc*512 + (j*32 + m2*8)*2) ^ ((vc & 7) << 4);
            f16x8 hv = *(const f16x8*)(yh + off);
            f16x8 lv = *(const f16x8*)(yl + off);
            #pragma unroll
            for (int e = 0; e < 8; ++e) {
                float val = (float)hv[e] + (float)lv[e];
                a1 += val; a2 += val * val;
            }
        }
        a1 += __shfl_xor(a1, 1); a2 += __shfl_xor(a2, 1);
        a1 += __shfl_xor(a1, 2); a2 += __shfl_xor(a2, 2);
        a1 += __shfl_xor(a1, 4); a2 += __shfl_xor(a2, 4);
        if (j == 0) {
            if (v < V_) {
                float mu  = a1 * (1.0f/256.0f);
                float var = a2 * (1.0f/256.0f) - mu * mu;
                sm.s_mu[v] = mu;
                sm.s_rs[v] = rsqrtf(var + 1e-5f);
            } else { sm.s_mu[v] = 0.0f; sm.s_rs[v] = 0.0f; }
        }
    }
    // NO barrier: GEMM below only READS ysh/ysl (no writer until post-GEMM
    // sync); s_mu/s_rs visibility is covered by that same sync.

    // s1/s2 for this lane's 16 output columns (issued early, L2-hot)
    float sv1[2][4], sv2[2][4];
    #pragma unroll
    for (int h = 0; h < 2; ++h)
        #pragma unroll
        for (int j = 0; j < 4; ++j) {
            const int e = h*256 + (wv*4 + j)*16 + l15;
            sv1[h][j] = s1p[e];
            sv2[h][j] = s2p[e];
        }

    // ---------------- GEMM: G[v][e] = sum_c x[v][c]*W'[e][c], f16 split-x3 ---
    f32x4 acc[2][2][4];
    #pragma unroll
    for (int h = 0; h < 2; ++h)
        #pragma unroll
        for (int m = 0; m < 2; ++m)
            #pragma unroll
            for (int j = 0; j < 4; ++j)
                acc[h][m][j] = (f32x4){0.f, 0.f, 0.f, 0.f};

    const char* bbase = (const char*)wsp + (size_t)lane * 16 + (size_t)(wv*4) * 2048;
    const int r1 = (16 + l15) < 24 ? (16 + l15) : 24;   // row clamp (acc rows
                                                        // >=25 masked later)
    for (int ch = 0; ch < 8; ++ch) {
        const int kb = (ch*32 + q4*8) * 2;
        const int o0 = (l15*512 + kb) ^ ((l15 & 7) << 4);
        const int o1 = (r1 *512 + kb) ^ ((r1  & 7) << 4);
        f16x8 Ah0 = *(const f16x8*)(yh + o0);
        f16x8 Ah1 = *(const f16x8*)(yh + o1);
        f16x8 Al0 = *(const f16x8*)(yl + o0);
        f16x8 Al1 = *(const f16x8*)(yl + o1);
        #pragma unroll
        for (int half = 0; half < 2; ++half) {
            const char* cb = bbase + (size_t)(half*8 + ch) * 16 * 2048;
            #pragma unroll
            for (int j = 0; j < 4; ++j) {
                const char* pj = cb + (size_t)j * 2048;
                f16x8 Bh = *(const f16x8*)pj;
                f16x8 Bl = *(const f16x8*)(pj + 1024);
                acc[half][0][j] = __builtin_amdgcn_mfma_f32_16x16x32_f16(Ah0, Bh, acc[half][0][j], 0, 0, 0);
                acc[half][0][j] = __builtin_amdgcn_mfma_f32_16x16x32_f16(Al0, Bh, acc[half][0][j], 0, 0, 0);
                acc[half][0][j] = __builtin_amdgcn_mfma_f32_16x16x32_f16(Ah0, Bl, acc[half][0][j], 0, 0, 0);
                acc[half][1][j] = __builtin_amdgcn_mfma_f32_16x16x32_f16(Ah1, Bh, acc[half][1][j], 0, 0, 0);
                acc[half][1][j] = __builtin_amdgcn_mfma_f32_16x16x32_f16(Al1, Bh, acc[half][1][j], 0, 0, 0);
                acc[half][1][j] = __builtin_amdgcn_mfma_f32_16x16x32_f16(Ah1, Bl, acc[half][1][j], 0, 0, 0);
            }
        }
    }
    __syncthreads();   // ysh/ysl reads done; s_mu visible; qk may be written

    // per-row LN constants for this thread's 8 accumulator rows
    f32x4 mu4[2], rs4[2];
    mu4[0] = *(const f32x4*)&sm.s_mu[q4*4];
    mu4[1] = *(const f32x4*)&sm.s_mu[16 + q4*4];
    rs4[0] = *(const f32x4*)&sm.s_rs[q4*4];
    rs4[1] = *(const f32x4*)&sm.s_rs[16 + q4*4];

    // ---------------- Attention via MFMA (per-wave, 2 heads) ------------------
    char* qh = (char*)&sm.u.qk[wv][0][0][0];
    char* ql = qh + 3200;

    #pragma unroll
    for (int hh = 0; hh < 2; ++hh) {
        // ---- LN epilogue + stage this head's Q,K (hi/lo f16) ----
        #pragma unroll
        for (int half = 0; half < 2; ++half)
            #pragma unroll
            for (int jj = 0; jj < 2; ++jj) {
                const int   j  = 2*hh + jj;
                const float c1 = sv1[half][j];
                const float c2 = sv2[half][j];
                const int  col = half*32 + jj*16 + l15;
                #pragma unroll
                for (int mt = 0; mt < 2; ++mt)
                    #pragma unroll
                    for (int r = 0; r < 4; ++r) {
                        const int row = mt*16 + q4*4 + r;
                        if (row < V_) {
                            float tv  = fmaf(-mu4[mt][r], c1, acc[half][mt][j][r]);
                            float val = fmaf(rs4[mt][r], tv, c2);
                            _Float16 h = (_Float16)val;
                            const int off = (row*128 + col*2) ^ ((row & 7) << 4);
                            *(_Float16*)(qh + off) = h;
                            *(_Float16*)(ql + off) = (_Float16)(val - (float)h);
                        }
                    }
            }
        // same-wave DS ops are in-order; compiler inserts lgkmcnt waits

        // ---- fragment reads (A = K rows, B = Q rows); rows >=25 clamp to 24 --
        f16x8 Kh[2], Kl[2], Qh[2], Ql[2];
        #pragma unroll
        for (int tt = 0; tt < 2; ++tt) {
            int rr = tt*16 + l15; if (rr > 24) rr = 24;
            const int swz = (rr & 7) << 4;
            const int oK  = (rr*128 + 64 + q4*16) ^ swz;
            const int oQ  = (rr*128 +      q4*16) ^ swz;
            Kh[tt] = *(const f16x8*)(qh + oK);
            Kl[tt] = *(const f16x8*)(ql + oK);
            Qh[tt] = *(const f16x8*)(qh + oQ);
            Ql[tt] = *(const f16x8*)(ql + oQ);
        }

        // ---- D[jt][it] = K·Q^T, split-x3 (12 MFMA per head) ----
        f32x4 D[2][2];
        #pragma unroll
        for (int jt = 0; jt < 2; ++jt)
            #pragma unroll
            for (int it = 0; it < 2; ++it) {
                f32x4 d = (f32x4){0.f, 0.f, 0.f, 0.f};
                d = __builtin_amdgcn_mfma_f32_16x16x32_f16(Kh[jt], Qh[it], d, 0, 0, 0);
                d = __builtin_amdgcn_mfma_f32_16x16x32_f16(Kl[jt], Qh[it], d, 0, 0, 0);
                d = __builtin_amdgcn_mfma_f32_16x16x32_f16(Kh[jt], Ql[it], d, 0, 0, 0);
                D[jt][it] = d;
            }

        // ---- softmax over keys + store ----
        float* op = out + (size_t)nt * 5000 + (wv*2 + hh) * 625;
        #pragma unroll
        for (int it = 0; it < 2; ++it) {
            const int i = it*16 + l15;          // query index (col = l15)
            float pv[2][4];
            float mx = -3.0e38f;
            #pragma unroll
            for (int jt = 0; jt < 2; ++jt)
                #pragma unroll
                for (int r = 0; r < 4; ++r) {
                    const int j = jt*16 + q4*4 + r;   // key index (row)
                    float v = (j < V_) ? D[jt][it][r] : -3.0e38f;
                    pv[jt][r] = v;
                    mx = fmaxf(mx, v);
                }
            mx = fmaxf(mx, __shfl_xor(mx, 16));
            mx = fmaxf(mx, __shfl_xor(mx, 32));
            float sum = 0.0f;
            #pragma unroll
            for (int jt = 0; jt < 2; ++jt)
                #pragma unroll
                for (int r = 0; r < 4; ++r) {
                    float e = exp2f((pv[jt][r] - mx) * KS_);
                    pv[jt][r] = e;
                    sum += e;
                }
            sum += __shfl_xor(sum, 16);
            sum += __shfl_xor(sum, 32);
            const float rcp = 1.0f / sum;
            if (i < V_) {
                #pragma unroll
                for (int jt = 0; jt < 2; ++jt)
                    #pragma unroll
                    for (int r = 0; r < 4; ++r) {
                        const int j = jt*16 + q4*4 + r;
                        if (j < V_) op[i*25 + j] = pv[jt][r] * rcp;
                    }
            }
        }
    }
}

extern "C" void kernel_launch(void* const* d_in, const int* in_sizes, int n_in,
                              void* d_out, int out_size, void* d_ws, size_t ws_size,
                              hipStream_t stream) {
    const float* x     = (const float*)d_in[0];
    const float* gamma = (const float*)d_in[1];
    const float* beta  = (const float*)d_in[2];
    const float* W     = (const float*)d_in[3];
    const float* b     = (const float*)d_in[4];
    char* ws = (char*)d_ws;
    float* out = (float*)d_out;

    prep_w<<<dim3(66), dim3(256), 0, stream>>>(W, gamma, beta, b, ws);
    fused_ln_qk_attn<<<dim3(NB), dim3(256), 0, stream>>>(
        x, (const _Float16*)ws,
        (const float*)(ws + 512*1024),
        (const float*)(ws + 512*1024 + 2048),
        out);
}